// Round 5
// baseline (2632.296 us; speedup 1.0000x reference)
//
#include <hip/hip_runtime.h>
#include <hip/hip_bf16.h>
#include <stdint.h>

// GRU-D encoder, MI355X persistent-kernel implementation, round 5.
// B=256, S=200, D=64, H=512, TD=8.
// Per 16-row chain (rb): 8 gate WGs (each wave owns 16 cols of z,r,Uh with
// truly register-resident weights: 48 frags = 192 VGPR; barrier-free,
// LDS-staging-free critical path; per-wave flag STORES + all-lane polls),
// 2 paced x-part producer WGs, 1 paced gamma producer WG.
// 11 WGs/rb x 16 rb = 176 WGs. All spins fuel-bounded (fail fast, no hang).

typedef unsigned short u16;
typedef unsigned int   u32;
typedef unsigned long long u64;
typedef short bfrag  __attribute__((ext_vector_type(8)));
typedef u16   u16x8  __attribute__((ext_vector_type(8)));
typedef float f32x4  __attribute__((ext_vector_type(4)));

#define NB 256
#define NS 200
#define ND 64
#define NH 512

#define MFMA(a,b,c) __builtin_amdgcn_mfma_f32_16x16x32_bf16((a),(b),(c),0,0,0)

union UQ  { u16x8 h; bfrag s; u64 u[2]; uint4 q; };
union UF2 { float f[2]; u64 u; };

__device__ __forceinline__ float b2f(u16 v){ union { float f; u32 u; } c; c.u = ((u32)v) << 16; return c.f; }
__device__ __forceinline__ u16 f2b(float f){ union { float f; u32 u; } c; c.f = f; u32 r = c.u + 0x7FFFu + ((c.u >> 16) & 1u); return (u16)(r >> 16); }
__device__ __forceinline__ float sigm(float x){ return 1.f / (1.f + __expf(-x)); }
__device__ __forceinline__ float tanh_f(float x){ return 1.f - 2.f / (1.f + __expf(2.f * x)); }

// agent-scope (coherence-point) ops: cross-XCD visible without L2 inv/wb fences
__device__ __forceinline__ u64 cload64(const void* p){
  return __hip_atomic_load((const u64*)p, __ATOMIC_RELAXED, __HIP_MEMORY_SCOPE_AGENT);
}
__device__ __forceinline__ void cstore64(void* p, u64 v){
  __hip_atomic_store((u64*)p, v, __ATOMIC_RELAXED, __HIP_MEMORY_SCOPE_AGENT);
}
__device__ __forceinline__ u32 cload32(const u32* p){
  return __hip_atomic_load(p, __ATOMIC_RELAXED, __HIP_MEMORY_SCOPE_AGENT);
}
__device__ __forceinline__ void cstore32(u32* p, u32 v){
  __hip_atomic_store(p, v, __ATOMIC_RELAXED, __HIP_MEMORY_SCOPE_AGENT);
}
// Wave-uniform vector poll: lane polls base[widx]; exits when ALL lanes'
// words reach tgt. Fuel-bounded (uniform exit) -> fail fast, no GPU hang.
__device__ __forceinline__ bool spin_vec(const u32* base, int widx, u32 tgt){
  const u32* p = base + widx;
  int fuel = 1 << 21;
  while (true) {
    u32 v = cload32(p);
    if (__all(v >= tgt)) return true;
    __builtin_amdgcn_s_sleep(2);
    if (--fuel == 0) return false;
  }
}
// load 8 consecutive f32 of a weight row, round to bf16 MFMA fragment
__device__ __forceinline__ bfrag ldfrag(const float* src){
  f32x4 lo = *(const f32x4*)src;
  f32x4 hi = *(const f32x4*)(src + 4);
  UQ z;
  z.h[0]=f2b(lo[0]); z.h[1]=f2b(lo[1]); z.h[2]=f2b(lo[2]); z.h[3]=f2b(lo[3]);
  z.h[4]=f2b(hi[0]); z.h[5]=f2b(hi[1]); z.h[6]=f2b(hi[2]); z.h[7]=f2b(hi[3]);
  return z.s;
}

// ---------------- setup kernels ----------------

__global__ void transpose_k(const float* __restrict__ Wout, float* __restrict__ WT){
  int i = blockIdx.x * 256 + threadIdx.x;
  if (i < 520 * 512) { int k = i >> 9, ho = i & 511; WT[i] = Wout[ho * 520 + k]; }
}

__global__ void mean1_k(const float* __restrict__ x, const float* __restrict__ mask,
                        float* __restrict__ PX, float* __restrict__ PM){
  int s = blockIdx.x, tid = threadIdx.x;
  __shared__ float lx[256], lm[256];
  float xa = 0.f, ma = 0.f;
  for (int i = tid; i < NB * ND; i += 256) {
    int b = i >> 6, d = i & 63;
    size_t ix = ((size_t)b * NS + s) * 64 + d;
    float m = mask[ix];
    xa += m * x[ix]; ma += m;
  }
  lx[tid] = xa; lm[tid] = ma;
  __syncthreads();
  if (tid < 64) {
    PX[(size_t)s * 64 + tid] = lx[tid] + lx[tid + 64] + lx[tid + 128] + lx[tid + 192];
    PM[(size_t)s * 64 + tid] = lm[tid] + lm[tid + 64] + lm[tid + 128] + lm[tid + 192];
  }
}

__global__ void mean2_k(const float* __restrict__ PX, const float* __restrict__ PM,
                        float* __restrict__ XMEAN){
  int d = threadIdx.x;
  float sx = 0.f, sm = 0.f;
  for (int s = 0; s < NS; ++s){ sx += PX[s * 64 + d]; sm += PM[s * 64 + d]; }
  XMEAN[d] = sx / fmaxf(sm, 1.f);
}

// per-(b,d) time chains: delta scan, x_last scan, x_hat; writes [s][b][d] bf16
__global__ void prep_k(const float* __restrict__ x, const float* __restrict__ mask,
                       const float* __restrict__ tc, const float* __restrict__ wdgx,
                       const float* __restrict__ bdgx, const float* __restrict__ XMEAN,
                       u16* __restrict__ XHAT, u16* __restrict__ MASKB, u16* __restrict__ DELTA){
  int g = blockIdx.x * 256 + threadIdx.x;
  int b = g >> 6, d = g & 63;
  float xmean = XMEAN[d], wx = wdgx[d], bx = bdgx[d];
  float xl = 0.f, del = 0.f, tprev = 0.f, mprev = 1.f;
  for (int s = 0; s < NS; ++s){
    float tv = tc[b * NS + s];
    float dtv = (s == 0) ? 0.f : (tv - tprev);
    tprev = tv;
    del = dtv + (1.f - mprev) * del;
    size_t ix = ((size_t)b * NS + s) * 64 + d;
    float m = mask[ix], xv = x[ix];
    float gx = __expf(-fmaxf(0.f, wx * del + bx));
    float xh = m * xv + (1.f - m) * (gx * xl + (1.f - gx) * xmean);
    size_t ox = ((size_t)s * NB + b) * 64 + d;
    XHAT[ox] = f2b(xh); MASKB[ox] = f2b(m); DELTA[ox] = f2b(del);
    xl = m * xv + (1.f - m) * xl;
    mprev = m;
  }
}

// ---------------- persistent recurrent kernel ----------------
// grid = 176 WGs (16 rb x 11), 256 threads (4 waves).
// role 0..7 : gate WG; wave owns 16 cols (cw = role*64+wid*16) of z, r, Uh.
//             Barrier-free: direct global A-frag loads, per-wave flag stores.
// role 8..9 : x-part producer (cols p*768..+768 of [z|r|h] pre-activations)
// role 10   : gamma producer.
// Flags per rb (stride 128 u32): FH[32] (+0), FR[32] (+32), FX[2] (+64), FG (+80).
// Flag word value = number of steps completed by that publisher.
__global__ __launch_bounds__(256, 1) void grud_rnn(
    const float* __restrict__ Um, const float* __restrict__ Wm, const float* __restrict__ Vm,
    const float* __restrict__ bv, const float* __restrict__ Wdg, const float* __restrict__ bdg,
    const u16* __restrict__ XHAT, const u16* __restrict__ MASKB, const u16* __restrict__ DELTA,
    u16* __restrict__ HDECB, u16* __restrict__ RHB, u16* __restrict__ XPART,
    u16* __restrict__ GAMB, u16* __restrict__ HALL, u32* __restrict__ flags)
{
  const int tid = threadIdx.x, lane = tid & 63, wid = tid >> 6, bid = blockIdx.x;
  const int rb = bid / 11, role = bid % 11, m0 = rb * 16;
  const int l16 = lane & 15, krow = lane >> 4;
  const int r4 = lane >> 2, c4 = (lane & 3) * 4, cb = (lane & 3) * 8;
  u32* FH = flags + rb * 128;
  u32* FR = FH + 32;
  u32* FX = FH + 64;
  u32* FG = FH + 80;

  __shared__ u16 hpanel[16 * 16 * 8];   // producer staging only (4 KB)
  __shared__ float xb[4][16 * 33];      // per-wave transpose scratch
  __shared__ int s_ab;
  float* xw = xb[wid];
  const f32x4 Z4 = {0.f, 0.f, 0.f, 0.f};
  if (tid == 0) s_ab = 0;
  __syncthreads();

  if (role < 8) {
    // ================= gate WG (barrier-free per-wave hot loop) =========
    const int gw = role * 4 + wid;          // publisher index 0..31
    const int cw = role * 64 + wid * 16;    // wave's 16-col strip base
    bfrag BUz[16], BUr[16], BUh[16];        // 48 frags = 192 VGPRs, resident
    #pragma unroll
    for (int kk = 0; kk < 16; ++kk) {
      const size_t ko = (size_t)(kk * 32 + krow * 8);
      BUz[kk] = ldfrag(Um + (size_t)(       cw + l16) * 512 + ko);
      BUr[kk] = ldfrag(Um + (size_t)(512  + cw + l16) * 512 + ko);
      BUh[kk] = ldfrag(Um + (size_t)(1024 + cw + l16) * 512 + ko);
    }

    for (int t = 0; t < NS; ++t) {
      // xpart / gamma (producers run ~2 steps ahead; usually no wait)
      if (!spin_vec(FX, lane & 1, (u32)(t + 1))) return;
      const u16* xpb = XPART + (((size_t)(t & 1) * 16 + rb) * 16 + r4) * 1536 + cw + c4;
      u64 xzu = cload64(xpb);
      u64 xru = cload64(xpb + 512);
      u64 xhu = cload64(xpb + 1024);
      u64 gmu = 0;
      if (t + 1 < NS) {
        if (!spin_vec(FG, 0, (u32)(t + 1))) return;
        gmu = cload64(GAMB + (((size_t)((t + 1) & 1) * 16 + rb) * 16 + r4) * 512 + cw + c4);
      }
      // ---- hop 1: h_dec(t) ready -> direct per-lane A-frag loads ----
      UQ HA[16]; u64 hdu = 0;
      if (t > 0) {
        if (!spin_vec(FH, lane & 31, (u32)t)) return;
        hdu = cload64(HDECB + (size_t)(m0 + r4) * 512 + cw + c4);
        #pragma unroll
        for (int kk = 0; kk < 16; ++kk) {
          const u16* p = HDECB + (size_t)(m0 + l16) * 512 + kk * 32 + krow * 8;
          HA[kk].u[0] = cload64(p); HA[kk].u[1] = cload64(p + 4);
        }
      } else {
        #pragma unroll
        for (int kk = 0; kk < 16; ++kk) { HA[kk].u[0] = 0; HA[kk].u[1] = 0; }
      }
      // ---- r GEMM (16 MFMA) ----
      f32x4 ar = Z4;
      #pragma unroll
      for (int kk = 0; kk < 16; ++kk) ar = MFMA(HA[kk].s, BUr[kk], ar);
      #pragma unroll
      for (int j = 0; j < 4; ++j) xw[(krow * 4 + j) * 17 + l16] = ar[j];
      UQ xr_; xr_.u[0] = xru; UQ hd_; hd_.u[0] = hdu;
      UQ rh_;
      #pragma unroll
      for (int q = 0; q < 4; ++q) {
        float rv = sigm(b2f(xr_.h[q]) + xw[r4 * 17 + c4 + q]);
        rh_.h[q] = f2b(rv * b2f(hd_.h[q]));
      }
      cstore64(RHB + (size_t)(m0 + r4) * 512 + cw + c4, rh_.u[0]);
      asm volatile("s_waitcnt vmcnt(0)" ::: "memory");
      if (lane == 0) cstore32(FR + gw, (u32)(t + 1));
      // ---- z GEMM fills the rh round-trip ----
      f32x4 az = Z4;
      #pragma unroll
      for (int kk = 0; kk < 16; ++kk) az = MFMA(HA[kk].s, BUz[kk], az);
      #pragma unroll
      for (int j = 0; j < 4; ++j) xw[(krow * 4 + j) * 17 + l16] = az[j];
      UQ xz_; xz_.u[0] = xzu;
      float zz[4];
      #pragma unroll
      for (int q = 0; q < 4; ++q) zz[q] = sigm(b2f(xz_.h[q]) + xw[r4 * 17 + c4 + q]);
      // ---- hop 2: rh all-gather -> Uh GEMM ----
      if (!spin_vec(FR, lane & 31, (u32)(t + 1))) return;
      UQ RA[16];
      #pragma unroll
      for (int kk = 0; kk < 16; ++kk) {
        const u16* p = RHB + (size_t)(m0 + l16) * 512 + kk * 32 + krow * 8;
        RA[kk].u[0] = cload64(p); RA[kk].u[1] = cload64(p + 4);
      }
      f32x4 ah = Z4;
      #pragma unroll
      for (int kk = 0; kk < 16; ++kk) ah = MFMA(RA[kk].s, BUh[kk], ah);
      #pragma unroll
      for (int j = 0; j < 4; ++j) xw[(krow * 4 + j) * 17 + l16] = ah[j];
      UQ xh_; xh_.u[0] = xhu; UQ gm_; gm_.u[0] = gmu;
      UQ hw_, hdn_;
      float hn[4];
      #pragma unroll
      for (int q = 0; q < 4; ++q) {
        float til = tanh_f(b2f(xh_.h[q]) + xw[r4 * 17 + c4 + q]);
        hn[q] = (1.f - zz[q]) * b2f(hd_.h[q]) + zz[q] * til;
        hw_.h[q] = f2b(hn[q]);
      }
      if (t + 1 < NS) {   // publish h_dec(t+1) = gamma(t+1) * h_new
        #pragma unroll
        for (int q = 0; q < 4; ++q) hdn_.h[q] = f2b(b2f(gm_.h[q]) * hn[q]);
        cstore64(HDECB + (size_t)(m0 + r4) * 512 + cw + c4, hdn_.u[0]);
      }
      asm volatile("s_waitcnt vmcnt(0)" ::: "memory");
      if (lane == 0) cstore32(FH + gw, (u32)(t + 1));
      // HALL store off the critical path (read only by attn_k later)
      *(u64*)(HALL + ((size_t)t * NB + m0 + r4) * 512 + cw + c4) = hw_.u[0];
    }
  } else if (role < 10) {
    // ================= x-part producer =================
    const int p = role - 8;
    const int wbase = p * 768 + wid * 192;   // wave col base in [0,1536)
    bfrag BW[12][2], BV2[12][2];
    #pragma unroll
    for (int ct = 0; ct < 12; ++ct)
      #pragma unroll
      for (int kx = 0; kx < 2; ++kx) {
        BW[ct][kx]  = ldfrag(Wm + (size_t)(wbase + ct * 16 + l16) * 64 + kx * 32 + krow * 8);
        BV2[ct][kx] = ldfrag(Vm + (size_t)(wbase + ct * 16 + l16) * 64 + kx * 32 + krow * 8);
      }
    float bias6[6][8];
    #pragma unroll
    for (int grp = 0; grp < 6; ++grp)
      #pragma unroll
      for (int q = 0; q < 8; ++q) bias6[grp][q] = bv[wbase + grp * 32 + cb + q];

    for (int t = 0; t < NS; ++t) {
      bool ok = (t < 2) || spin_vec(FH, lane & 31, (u32)(t - 1));
      if (!ok) s_ab = 1;
      { const int kb = tid >> 4, row = tid & 15;
        const u16* sp = (kb < 8 ? XHAT : MASKB) + ((size_t)t * NB + m0 + row) * 64 + (kb & 7) * 8;
        *(uint4*)&hpanel[(kb * 16 + row) * 8] = *(const uint4*)sp; }
      __syncthreads();
      if (s_ab) break;
      u16* orow_ = XPART + (((size_t)(t & 1) * 16 + rb) * 16 + r4) * 1536 + wbase;
      #pragma unroll
      for (int grp = 0; grp < 6; ++grp) {
        f32x4 ac0 = Z4, ac1 = Z4;
        #pragma unroll
        for (int kx = 0; kx < 2; ++kx) {
          bfrag ax = *(const bfrag*)&hpanel[((kx * 4 + krow) * 16 + l16) * 8];
          ac0 = MFMA(ax, BW[grp*2][kx], ac0); ac1 = MFMA(ax, BW[grp*2+1][kx], ac1);
          bfrag am = *(const bfrag*)&hpanel[((8 + kx * 4 + krow) * 16 + l16) * 8];
          ac0 = MFMA(am, BV2[grp*2][kx], ac0); ac1 = MFMA(am, BV2[grp*2+1][kx], ac1);
        }
        #pragma unroll
        for (int j = 0; j < 4; ++j) { xw[(krow*4+j)*33 + l16] = ac0[j]; xw[(krow*4+j)*33 + 16 + l16] = ac1[j]; }
        UQ ov;
        #pragma unroll
        for (int q = 0; q < 8; ++q) ov.h[q] = f2b(xw[r4 * 33 + cb + q] + bias6[grp][q]);
        cstore64(orow_ + grp * 32 + cb, ov.u[0]); cstore64(orow_ + grp * 32 + cb + 4, ov.u[1]);
      }
      asm volatile("s_waitcnt vmcnt(0)" ::: "memory");
      __syncthreads();
      if (tid == 0) cstore32(FX + p, (u32)(t + 1));
    }
  } else {
    // ================= gamma producer =================
    bfrag BG[8][2];
    #pragma unroll
    for (int ct = 0; ct < 8; ++ct)
      #pragma unroll
      for (int kx = 0; kx < 2; ++kx)
        BG[ct][kx] = ldfrag(Wdg + (size_t)(wid * 128 + ct * 16 + l16) * 64 + kx * 32 + krow * 8);
    float gb4[4][8];
    #pragma unroll
    for (int grp = 0; grp < 4; ++grp)
      #pragma unroll
      for (int q = 0; q < 8; ++q) gb4[grp][q] = bdg[wid * 128 + grp * 32 + cb + q];

    for (int tt = 1; tt < NS; ++tt) {
      bool ok = (tt < 3) || spin_vec(FH, lane & 31, (u32)(tt - 2));
      if (!ok) s_ab = 1;
      if (tid < 128) {
        const int kb = tid >> 4, row = tid & 15;
        const u16* sp = DELTA + ((size_t)tt * NB + m0 + row) * 64 + kb * 8;
        *(uint4*)&hpanel[(kb * 16 + row) * 8] = *(const uint4*)sp;
      }
      __syncthreads();
      if (s_ab) break;
      u16* orow_ = GAMB + (((size_t)(tt & 1) * 16 + rb) * 16 + r4) * 512 + wid * 128;
      #pragma unroll
      for (int grp = 0; grp < 4; ++grp) {
        f32x4 ac0 = Z4, ac1 = Z4;
        #pragma unroll
        for (int kx = 0; kx < 2; ++kx) {
          bfrag a = *(const bfrag*)&hpanel[((kx * 4 + krow) * 16 + l16) * 8];
          ac0 = MFMA(a, BG[grp*2][kx], ac0); ac1 = MFMA(a, BG[grp*2+1][kx], ac1);
        }
        #pragma unroll
        for (int j = 0; j < 4; ++j) { xw[(krow*4+j)*33 + l16] = ac0[j]; xw[(krow*4+j)*33 + 16 + l16] = ac1[j]; }
        UQ ov;
        #pragma unroll
        for (int q = 0; q < 8; ++q)
          ov.h[q] = f2b(__expf(-fmaxf(0.f, xw[r4 * 33 + cb + q] + gb4[grp][q])));
        cstore64(orow_ + grp * 32 + cb, ov.u[0]); cstore64(orow_ + grp * 32 + cb + 4, ov.u[1]);
      }
      asm volatile("s_waitcnt vmcnt(0)" ::: "memory");
      __syncthreads();
      if (tid == 0) cstore32(FG, (u32)tt);
    }
  }
}

// ---------------- post kernels ----------------

__global__ void attn_k(const u16* __restrict__ HALL, const float* __restrict__ av,
                       float* __restrict__ ATTN){
  const int b = blockIdx.x, tid = threadIdx.x, lane = tid & 63, wid = tid >> 6;
  __shared__ float avs[512], wgt[256], red[8];
  for (int i = tid; i < 512; i += 256) avs[i] = av[i];
  __syncthreads();
  float val = -3.0e38f;
  if (tid < NS) {
    const u16* hp = HALL + ((size_t)tid * NB + b) * 512;
    float acc = 0.f;
    for (int h = 0; h < 512; h += 8) {
      UQ w; w.q = *(const uint4*)(hp + h);
      #pragma unroll
      for (int j = 0; j < 8; ++j) acc += b2f(w.h[j]) * avs[h + j];
    }
    val = acc * 0.04419417382415922f;   // 1/sqrt(512)
  }
  float m = val;
  #pragma unroll
  for (int off = 32; off; off >>= 1) m = fmaxf(m, __shfl_xor(m, off, 64));
  if (lane == 0) red[wid] = m;
  __syncthreads();
  m = fmaxf(fmaxf(red[0], red[1]), fmaxf(red[2], red[3]));
  float e = (tid < NS) ? __expf(val - m) : 0.f;
  float sum = e;
  #pragma unroll
  for (int off = 32; off; off >>= 1) sum += __shfl_xor(sum, off, 64);
  if (lane == 0) red[4 + wid] = sum;
  __syncthreads();
  const float ssum = red[4] + red[5] + red[6] + red[7];
  wgt[tid] = e / ssum;
  __syncthreads();
  float a0 = 0.f, a1 = 0.f;
  const int h0 = tid * 2;
  for (int s = 0; s < NS; ++s) {
    float w = wgt[s];
    u32 pr = *(const u32*)(HALL + ((size_t)s * NB + b) * 512 + h0);
    a0 += w * b2f((u16)(pr & 0xFFFFu));
    a1 += w * b2f((u16)(pr >> 16));
  }
  ATTN[(size_t)b * 512 + h0] = a0;
  ATTN[(size_t)b * 512 + h0 + 1] = a1;
}

// 4 batch rows per WG: WT re-read traffic 256MB -> 64MB
__global__ void out_k(const float* __restrict__ ATTN, const float* __restrict__ Ain,
                      const float* __restrict__ WT, const float* __restrict__ bout,
                      float* __restrict__ OUT){
  const int g = blockIdx.x, tid = threadIdx.x;
  __shared__ float ah[4][520];
  for (int i = tid; i < 4 * 520; i += 256) {
    int bb = i / 520, k = i % 520;
    int b = g * 4 + bb;
    ah[bb][k] = (k < 512) ? ATTN[(size_t)b * 512 + k] : Ain[b * 8 + (k - 512)];
  }
  __syncthreads();
  #pragma unroll
  for (int part = 0; part < 2; ++part) {
    const int ho = part * 256 + tid;
    float a0 = bout[ho], a1 = a0, a2 = a0, a3 = a0;
    for (int k = 0; k < 520; ++k) {
      float w = WT[(size_t)k * 512 + ho];
      a0 += ah[0][k] * w; a1 += ah[1][k] * w; a2 += ah[2][k] * w; a3 += ah[3][k] * w;
    }
    OUT[(size_t)(g * 4 + 0) * 512 + ho] = a0;
    OUT[(size_t)(g * 4 + 1) * 512 + ho] = a1;
    OUT[(size_t)(g * 4 + 2) * 512 + ho] = a2;
    OUT[(size_t)(g * 4 + 3) * 512 + ho] = a3;
  }
}

// ---------------- host ----------------

extern "C" void kernel_launch(void* const* d_in, const int* in_sizes, int n_in,
                              void* d_out, int out_size, void* d_ws, size_t ws_size,
                              hipStream_t stream) {
  (void)in_sizes; (void)n_in; (void)out_size; (void)ws_size;
  const float* x    = (const float*)d_in[0];
  const float* a_in = (const float*)d_in[1];
  const float* tc   = (const float*)d_in[2];
  const float* mask = (const float*)d_in[3];
  const float* wdgx = (const float*)d_in[4];
  const float* bdgx = (const float*)d_in[5];
  const float* Wdgh = (const float*)d_in[6];
  const float* bdgh = (const float*)d_in[7];
  const float* Wm   = (const float*)d_in[8];
  const float* Um   = (const float*)d_in[9];
  const float* Vm   = (const float*)d_in[10];
  const float* bvv  = (const float*)d_in[11];
  const float* attv = (const float*)d_in[12];
  const float* Wout = (const float*)d_in[13];
  const float* bout = (const float*)d_in[14];

  char* ws = (char*)d_ws;
  size_t o = 0;
  auto al = [&](size_t sz) { size_t r = o; o += (sz + 255) & ~(size_t)255; return r; };
  u32*   flags = (u32*)  (ws + al(16 * 128 * 4));
  float* XMEAN = (float*)(ws + al(256));
  float* PX    = (float*)(ws + al((size_t)NS * 64 * 4));
  float* PM    = (float*)(ws + al((size_t)NS * 64 * 4));
  u16*   XHAT  = (u16*)  (ws + al((size_t)NS * NB * 64 * 2));
  u16*   MASKB = (u16*)  (ws + al((size_t)NS * NB * 64 * 2));
  u16*   DELTA = (u16*)  (ws + al((size_t)NS * NB * 64 * 2));
  u16*   HDECB = (u16*)  (ws + al((size_t)NB * NH * 2));
  u16*   RHB   = (u16*)  (ws + al((size_t)NB * NH * 2));
  u16*   XPART = (u16*)  (ws + al((size_t)2 * 16 * 16 * 1536 * 2));
  u16*   GAMB  = (u16*)  (ws + al((size_t)2 * 16 * 16 * 512 * 2));
  u16*   HALL  = (u16*)  (ws + al((size_t)NS * NB * NH * 2));
  float* ATTN  = (float*)(ws + al((size_t)NB * NH * 4));
  float* WT    = (float*)(ws + al((size_t)520 * 512 * 4));

  hipMemsetAsync(flags, 0, 16 * 128 * 4, stream);

  transpose_k<<<(520 * 512 + 255) / 256, 256, 0, stream>>>(Wout, WT);
  mean1_k<<<NS, 256, 0, stream>>>(x, mask, PX, PM);
  mean2_k<<<1, 64, 0, stream>>>(PX, PM, XMEAN);
  prep_k<<<NB * ND / 256, 256, 0, stream>>>(x, mask, tc, wdgx, bdgx, XMEAN, XHAT, MASKB, DELTA);
  grud_rnn<<<176, 256, 0, stream>>>(Um, Wm, Vm, bvv, Wdgh, bdgh, XHAT, MASKB, DELTA,
                                    HDECB, RHB, XPART, GAMB, HALL, flags);
  attn_k<<<NB, 256, 0, stream>>>(HALL, attv, ATTN);
  out_k<<<64, 256, 0, stream>>>(ATTN, a_in, WT, bout, (float*)d_out);
}